// Round 6
// baseline (121.265 us; speedup 1.0000x reference)
//
#include <hip/hip_runtime.h>
#include <math.h>

// STDP_84791244358141 — T=256, N_pre=N_post=1024, AP=AN=1, TP=TN=2, TE=1.
//
// MATH (VERIFIED r5: literal T-step scan == closed form bit-identically):
// with TE=1, e = e - e/1 + outer = outer exactly; output is the last step:
//     e[i][j] = x_T[i]*q_T[j] - p_T[i]*y_T[j]
// x_t = x + (p - x)/2 (pre-trace, updated before the e update), y likewise.
//
// ROUND-5 POST-MORTEM (the real bug, rounds 1-5): the test's error label
// "(bf16, ref=np)" is a HARDCODED f-string literal in the harness template —
// it does not indicate dtype. The reference output dtype is pre.dtype =
// FLOAT32. Writing bf16 halfwords into the f32 buffer made every f32
// readback ≈ the odd-indexed bf16 element at the wrong position -> the
// 0.91-0.935 decoupled errors across r1-r5, and r0's exact-dyadic absmax
// 0.49609375 (fp32 ref needs no rounding story). Fix: fp32 everywhere.
// Inputs are fp32 (proven: r1-vs-r2 error changed when read path changed).

constexpr int BLOCK = 256;

// Kernel 1: x/y finals + last spike rows into ws (4N floats).
// ws: [0,N)=x_T, [N,2N)=y_T, [2N,3N)=p_T, [3N,4N)=q_T
__global__ __launch_bounds__(BLOCK) void stdp_traces(
    const float* __restrict__ pre, const float* __restrict__ post,
    float* __restrict__ ws, int N, int T)
{
    const int gid = blockIdx.x * BLOCK + threadIdx.x;   // 0 .. 2N-1
    if (gid >= 2 * N) return;
    const float* __restrict__ src = (gid < N) ? pre : post;
    const int c = (gid < N) ? gid : gid - N;
    float v = 0.0f, last = 0.0f;
    for (int t = 0; t < T; ++t) {
        const float s = src[(size_t)t * N + c];   // coalesced across lanes
        v += (s - v) * 0.5f;    // == x + (-x + AP*p)/TP rounding sequence
        last = s;
    }
    ws[gid] = v;
    ws[2 * N + gid] = last;
}

// Kernel 2: out[i][j] = x_i*q_j - p_i*y_j, fp32, float4 stores.
__global__ __launch_bounds__(BLOCK) void stdp_outer(
    const float* __restrict__ ws, float* __restrict__ out, int N)
{
    const int i = blockIdx.x;
    const float x_i = ws[i];
    const float p_i = ws[2 * N + i];
    for (int j0 = threadIdx.x * 4; j0 < N; j0 += BLOCK * 4) {
        const float4 y4 = *reinterpret_cast<const float4*>(ws + N + j0);
        const float4 q4 = *reinterpret_cast<const float4*>(ws + 3 * N + j0);
        float4 o;
        o.x = x_i * q4.x - p_i * y4.x;
        o.y = x_i * q4.y - p_i * y4.y;
        o.z = x_i * q4.z - p_i * y4.z;
        o.w = x_i * q4.w - p_i * y4.w;
        *reinterpret_cast<float4*>(out + (size_t)i * N + j0) = o;
    }
}

// Fallback (ws too small): fused, traces recomputed per block in LDS.
__global__ __launch_bounds__(BLOCK) void stdp_fused(
    const float* __restrict__ pre, const float* __restrict__ post,
    float* __restrict__ out, int N, int T, int R)
{
    extern __shared__ float sh[];   // xs[N], ys[N], ps[N], qs[N]
    float* xs = sh; float* ys = sh + N; float* ps = sh + 2 * N; float* qs = sh + 3 * N;
    for (int c = threadIdx.x; c < N; c += BLOCK) {
        float xv = 0.0f, yv = 0.0f, pl = 0.0f, ql = 0.0f;
        for (int t = 0; t < T; ++t) {
            const float pv = pre [(size_t)t * N + c];
            const float qv = post[(size_t)t * N + c];
            xv += (pv - xv) * 0.5f;
            yv += (qv - yv) * 0.5f;
            pl = pv; ql = qv;
        }
        xs[c] = xv; ys[c] = yv; ps[c] = pl; qs[c] = ql;
    }
    __syncthreads();
    const int i0 = blockIdx.x * R;
    for (int r = 0; r < R; ++r) {
        const int i = i0 + r;
        if (i >= N) break;
        const float x_i = xs[i], p_i = ps[i];
        for (int j0 = threadIdx.x * 4; j0 < N; j0 += BLOCK * 4) {
            const float4 y4 = *reinterpret_cast<const float4*>(ys + j0);
            const float4 q4 = *reinterpret_cast<const float4*>(qs + j0);
            float4 o;
            o.x = x_i * q4.x - p_i * y4.x;
            o.y = x_i * q4.y - p_i * y4.y;
            o.z = x_i * q4.z - p_i * y4.z;
            o.w = x_i * q4.w - p_i * y4.w;
            *reinterpret_cast<float4*>(out + (size_t)i * N + j0) = o;
        }
    }
}

extern "C" void kernel_launch(void* const* d_in, const int* in_sizes, int n_in,
                              void* d_out, int out_size, void* d_ws, size_t ws_size,
                              hipStream_t stream)
{
    // Exact shape derivation (no square assumption):
    // in0 = T*N_pre, in1 = T*N_post, out = N_pre*N_post  =>  T = sqrt(in0*in1/out)
    const double t_d = sqrt((double)in_sizes[0] * (double)in_sizes[1] / (double)out_size);
    const int T = (int)(t_d + 0.5);
    const int N = in_sizes[0] / T;          // N_pre (== N_post here: 1024)

    const float* pre  = (const float*)d_in[0];
    const float* post = (const float*)d_in[1];
    float* out = (float*)d_out;

    const size_t ws_need = (size_t)4 * N * sizeof(float);
    if (ws_size >= ws_need) {
        float* ws = (float*)d_ws;
        stdp_traces<<<(2 * N + BLOCK - 1) / BLOCK, BLOCK, 0, stream>>>(pre, post, ws, N, T);
        stdp_outer <<<N, BLOCK, 0, stream>>>(ws, out, N);
    } else {
        const int R = 8;
        stdp_fused<<<(N + R - 1) / R, BLOCK, ws_need, stream>>>(pre, post, out, N, T, R);
    }
}

// Round 7
// 59.238 us; speedup vs baseline: 2.0471x; 2.0471x over previous
//
#include <hip/hip_runtime.h>
#include <math.h>

// STDP_84791244358141 — T=256, N=1024, AP=AN=1, TP=TN=2, TE=1. fp32 in/out.
//
// MATH (verified r5/r6, absmax 0.0 vs np ref): te=1 makes the e-carry dead;
//     e[i][j] = x_T[i]*q_T[j] - p_T[i]*y_T[j]
// with x_t = x + (p - x)/2 and p_T/q_T the last spike rows.
//
// R6 POST-MORTEM: stdp_traces was 102 us = 256 iters x ~900cyc HBM latency,
// fully serialized (8 blocks, 1 wave/SIMD, load->waitcnt->fma per iter;
// 256*900/2.4GHz = 96 us ~ observed). Fix: the trace filter is LINEAR ->
// split T into 8 segments/column (8x threads, 64 blocks) and batch 8
// carry-independent loads per drain. Segment partials combine exactly via
// power-of-two scaling: v = sum_s w_s * 2^(-L*(7-s)) (ldexpf; underflow->0
// matches the true decay). Reassociation error ~1 ulp << 2% threshold.

constexpr int BLOCK = 256;

// Fast traces: grid = 64 blocks (2 tensors x 32 col-groups), block = 8 segs
// x 32 cols. Requires T % 64 == 0 and N % 32 == 0.
// ws: [0,N)=x_T, [N,2N)=y_T, [2N,3N)=p_T, [3N,4N)=q_T
__global__ __launch_bounds__(BLOCK) void stdp_traces_seg(
    const float* __restrict__ pre, const float* __restrict__ post,
    float* __restrict__ ws, int N, int T)
{
    const int tid = threadIdx.x;
    const int seg = tid >> 5;                 // 0..7
    const int cof = tid & 31;
    const int b   = blockIdx.x;
    const int tensor  = b >> 5;               // 0 = pre, 1 = post
    const int colbase = (b & 31) << 5;
    const int col     = colbase + cof;
    const float* __restrict__ src = tensor ? post : pre;

    const int L  = T >> 3;                    // 32 for T=256
    const int t0 = seg * L;

    float v = 0.0f, last = 0.0f;
    for (int tb = 0; tb < L; tb += 8) {
        float tmp[8];
#pragma unroll
        for (int k = 0; k < 8; ++k)           // 8 independent loads, 1 drain
            tmp[k] = src[(size_t)(t0 + tb + k) * N + col];
#pragma unroll
        for (int k = 0; k < 8; ++k)
            v += (tmp[k] - v) * 0.5f;         // reference rounding sequence
        last = tmp[7];
    }

    __shared__ float part[BLOCK];
    part[tid] = ldexpf(v, -L * (7 - seg));    // exact pow2 scale; uflow -> 0
    __syncthreads();
    if (tid < 32) {
        float s = 0.0f;
#pragma unroll
        for (int k = 0; k < 8; ++k)           // ascending seg = ascending mag
            s += part[k * 32 + tid];
        ws[tensor * N + colbase + tid] = s;   // x or y final
    }
    if (seg == 7)
        ws[2 * N + tensor * N + col] = last;  // p_T or q_T
}

// Generic fallback (any T, N): one thread per column, sequential scan.
__global__ __launch_bounds__(BLOCK) void stdp_traces_gen(
    const float* __restrict__ pre, const float* __restrict__ post,
    float* __restrict__ ws, int N, int T)
{
    const int gid = blockIdx.x * BLOCK + threadIdx.x;
    if (gid >= 2 * N) return;
    const float* __restrict__ src = (gid < N) ? pre : post;
    const int c = (gid < N) ? gid : gid - N;
    float v = 0.0f, last = 0.0f;
    for (int t = 0; t < T; ++t) {
        const float s = src[(size_t)t * N + c];
        v += (s - v) * 0.5f;
        last = s;
    }
    ws[gid] = v;
    ws[2 * N + gid] = last;
}

// out[i][j] = x_i*q_j - p_i*y_j, float4 stores; one block per row.
__global__ __launch_bounds__(BLOCK) void stdp_outer(
    const float* __restrict__ ws, float* __restrict__ out, int N)
{
    const int i = blockIdx.x;
    const float x_i = ws[i];
    const float p_i = ws[2 * N + i];
    for (int j0 = threadIdx.x * 4; j0 < N; j0 += BLOCK * 4) {
        const float4 y4 = *reinterpret_cast<const float4*>(ws + N + j0);
        const float4 q4 = *reinterpret_cast<const float4*>(ws + 3 * N + j0);
        float4 o;
        o.x = x_i * q4.x - p_i * y4.x;
        o.y = x_i * q4.y - p_i * y4.y;
        o.z = x_i * q4.z - p_i * y4.z;
        o.w = x_i * q4.w - p_i * y4.w;
        *reinterpret_cast<float4*>(out + (size_t)i * N + j0) = o;
    }
}

extern "C" void kernel_launch(void* const* d_in, const int* in_sizes, int n_in,
                              void* d_out, int out_size, void* d_ws, size_t ws_size,
                              hipStream_t stream)
{
    // in0 = T*N_pre, in1 = T*N_post, out = N_pre*N_post => T = sqrt(in0*in1/out)
    const double t_d = sqrt((double)in_sizes[0] * (double)in_sizes[1] / (double)out_size);
    const int T = (int)(t_d + 0.5);
    const int N = in_sizes[0] / T;

    const float* pre  = (const float*)d_in[0];
    const float* post = (const float*)d_in[1];
    float* out = (float*)d_out;
    float* ws  = (float*)d_ws;                 // needs 4N floats = 16 KB

    if (T % 64 == 0 && N % 32 == 0) {
        stdp_traces_seg<<<2 * (N / 32), BLOCK, 0, stream>>>(pre, post, ws, N, T);
    } else {
        stdp_traces_gen<<<(2 * N + BLOCK - 1) / BLOCK, BLOCK, 0, stream>>>(pre, post, ws, N, T);
    }
    stdp_outer<<<N, BLOCK, 0, stream>>>(ws, out, N);
}